// Round 3
// baseline (2699.991 us; speedup 1.0000x reference)
//
#include <hip/hip_runtime.h>
#include <hip/hip_bf16.h>

#define RR 8
#define BB 32
#define CIN 21
#define CC 128
#define LL 4096
#define TT 32    // time-tile
#define GP 136   // sG row stride (shorts): 128 + 8 pad (272B rows, 16B-aligned)
#define PADT 132 // zeroed halo rows per batch (>= max shift 129)
#define LP (LL + PADT)

typedef short s16x8 __attribute__((ext_vector_type(8)));
typedef float f32x4 __attribute__((ext_vector_type(4)));

__device__ __forceinline__ unsigned short f2b(float f) {
    __hip_bfloat16 h = __float2bfloat16(f);
    return *reinterpret_cast<unsigned short*>(&h);
}
__device__ __forceinline__ float b2f(unsigned short u) {
    __hip_bfloat16 h;
    *reinterpret_cast<unsigned short*>(&h) = u;
    return __bfloat162float(h);
}
__device__ __forceinline__ unsigned int packsplit(float v) {
    unsigned short hi = f2b(v);
    unsigned short lo = f2b(v - b2f(hi));
    return ((unsigned int)hi << 16) | (unsigned int)lo;
}
__device__ __forceinline__ float unpacksum(unsigned int u) {
    return b2f((unsigned short)(u >> 16)) + b2f((unsigned short)(u & 0xffffu));
}

// 8 packed (hi|lo) uint32 -> s16x8 hi-plane + s16x8 lo-plane via v_perm
__device__ __forceinline__ void unpack8(const unsigned int* __restrict__ p, s16x8& hi, s16x8& lo) {
    uint4 u0 = *reinterpret_cast<const uint4*>(p);
    uint4 u1 = *reinterpret_cast<const uint4*>(p + 4);
    union { int i[4]; s16x8 v; } H, L;
    H.i[0] = __builtin_amdgcn_perm(u0.y, u0.x, 0x07060302u);
    L.i[0] = __builtin_amdgcn_perm(u0.y, u0.x, 0x05040100u);
    H.i[1] = __builtin_amdgcn_perm(u0.w, u0.z, 0x07060302u);
    L.i[1] = __builtin_amdgcn_perm(u0.w, u0.z, 0x05040100u);
    H.i[2] = __builtin_amdgcn_perm(u1.y, u1.x, 0x07060302u);
    L.i[2] = __builtin_amdgcn_perm(u1.y, u1.x, 0x05040100u);
    H.i[3] = __builtin_amdgcn_perm(u1.w, u1.z, 0x07060302u);
    L.i[3] = __builtin_amdgcn_perm(u1.w, u1.z, 0x05040100u);
    hi = H.v; lo = L.v;
}

// ---- pack weights to split-bf16 (hi/lo) MFMA rows.
// Wsg[r][o][k]: o<128 signal, o>=128 gate; k<128 tap0 (t-off0), k>=128 tap1 (t-1).
// Wkr[r][o2][c]: o2<128 skip, o2>=128 res.
__global__ void prep_kernel(const float* __restrict__ sw, const float* __restrict__ gw,
                            const float* __restrict__ skw, const float* __restrict__ rew,
                            unsigned short* __restrict__ WsgH, unsigned short* __restrict__ WsgL,
                            unsigned short* __restrict__ WkrH, unsigned short* __restrict__ WkrL) {
    int idx = blockIdx.x * 256 + threadIdx.x;        // over R*256*256 = 524288
    int r = idx >> 16;
    int rem = idx & 65535;
    int o = rem >> 8;
    int k = rem & 255;
    int c = k & 127;
    int tap = k >> 7;
    float v = (o < 128) ? sw[(((r * 128 + o) * 128 + c) << 1) + tap]
                        : gw[(((r * 128 + (o - 128)) * 128 + c) << 1) + tap];
    unsigned short hi = f2b(v);
    WsgH[idx] = hi;
    WsgL[idx] = f2b(v - b2f(hi));
    if (idx < RR * 256 * 128) {
        int r2 = idx >> 15;
        int rem2 = idx & 32767;
        int o2 = rem2 >> 7;
        int c2 = rem2 & 127;
        float v2 = (o2 < 128) ? skw[(r2 * 128 + o2) * 128 + c2]
                              : rew[(r2 * 128 + (o2 - 128)) * 128 + c2];
        unsigned short hi2 = f2b(v2);
        WkrH[idx] = hi2;
        WkrL[idx] = f2b(v2 - b2f(hi2));
    }
}

// ---- zero the halo rows of both h buffers (epilogue never writes them)
__global__ void zero_pad_kernel(unsigned int* __restrict__ hA, unsigned int* __restrict__ hB) {
    int idx = blockIdx.x * 256 + threadIdx.x;        // over BB*PADT*CC
    int c = idx & 127;
    int r = (idx >> 7) % PADT;
    int b = idx / (PADT * 128);
    size_t off = ((size_t)b * LP + r) * CC + c;
    hA[off] = 0u;
    hB[off] = 0u;
}

// ---- input projection: h0 packed split-bf16 [b][PADT+t][c]
__global__ void proj_kernel(const float* __restrict__ x, const float* __restrict__ w0,
                            const float* __restrict__ b0, unsigned int* __restrict__ h0) {
    int idx = blockIdx.x * 256 + threadIdx.x;        // ((b*L)+t)*C + c
    int c = idx & 127;
    int t = (idx >> 7) & (LL - 1);
    int b = idx >> 19;
    const float* xb = x + (size_t)b * CIN * LL + t;
    const float* w = w0 + c * CIN;
    float acc = b0[c];
#pragma unroll
    for (int i = 0; i < CIN; i++) acc = fmaf(w[i], xb[i * LL], acc);
    h0[((size_t)b * LP + PADT + t) * CC + c] = packsplit(acc);
}

// ---- fused split-bf16 MFMA layer; 8 waves/block, each wave owns 16 output
// channels per GEMM (n=0: signal/skip, n=1: gate/res). A-fragments direct
// from global packed h; g kept in registers between GEMM1 and epilogue.
__global__ void __launch_bounds__(512, 4) layer_kernel(
    const unsigned int* __restrict__ hcur,     // packed [B][LP][C], data at row PADT
    unsigned int* __restrict__ hnext,
    float* __restrict__ skipbuf,               // f32 [B][L][C]
    const unsigned short* __restrict__ WsgH, const unsigned short* __restrict__ WsgL,
    const unsigned short* __restrict__ WkrH, const unsigned short* __restrict__ WkrL,
    const float* __restrict__ csw, const float* __restrict__ cgw,
    const float* __restrict__ z,
    float* __restrict__ out,                   // f32 [2][B][C][L] on last layer
    int off0, int first, int last) {
    __shared__ unsigned short sGhi[TT * GP];   // g^T hi [t][c]
    __shared__ unsigned short sGlo[TT * GP];

    int tid = threadIdx.x;
    int b = blockIdx.x >> 7;                   // 32 batches
    int t0 = (blockIdx.x & 127) * TT;          // 128 t-tiles

    int wave = tid >> 6;                       // 0..7
    int lane = tid & 63;
    int l15 = lane & 15;
    int quad = lane >> 4;

    // single base pointer; win1 (t-1) is a uniform element offset from win0 (t-off0)
    const unsigned int* hb = hcur + (size_t)b * LP * CC;
    const unsigned int* a0 = hb + (size_t)(PADT + t0 + l15 - off0) * CC + quad * 8;
    const int dwin = (off0 - 1) * CC;          // wave-uniform

    // ---- GEMM1: [sig;gate]^T[t][o], M=32, N=256, K=256, split-bf16 3-pass
    // wave's o-columns: n=0 -> signal ch (wave*16+l15), n=1 -> gate ch (same)
    f32x4 acc1[2][2];
#pragma unroll
    for (int m = 0; m < 2; m++)
#pragma unroll
        for (int n = 0; n < 2; n++) acc1[m][n] = (f32x4){0.f, 0.f, 0.f, 0.f};

#pragma unroll
    for (int kk = 0; kk < 8; kk++) {
        const int win = kk >> 2;               // compile-time after unroll
        const int chb = (kk & 3) * 32;
        s16x8 Ah[2], Al[2];
#pragma unroll
        for (int m = 0; m < 2; m++)
            unpack8(a0 + (win ? dwin : 0) + m * (16 * CC) + chb, Ah[m], Al[m]);
#pragma unroll
        for (int n = 0; n < 2; n++) {
            int o = (wave + 8 * n) * 16 + l15;
            s16x8 Bh = *(const s16x8*)(WsgH + o * 256 + kk * 32 + quad * 8);
            s16x8 Bl = *(const s16x8*)(WsgL + o * 256 + kk * 32 + quad * 8);
#pragma unroll
            for (int m = 0; m < 2; m++) {
                acc1[m][n] = __builtin_amdgcn_mfma_f32_16x16x32_bf16(Ah[m], Bh, acc1[m][n], 0, 0, 0);
                acc1[m][n] = __builtin_amdgcn_mfma_f32_16x16x32_bf16(Al[m], Bh, acc1[m][n], 0, 0, 0);
                acc1[m][n] = __builtin_amdgcn_mfma_f32_16x16x32_bf16(Ah[m], Bl, acc1[m][n], 0, 0, 0);
            }
        }
    }

    // ---- conditioning + gated activation; g kept in registers (c = wave*16+l15)
    float g[2][4];
    {
        const float* zb = z + (size_t)b * LL + t0;
        float cs = csw[wave * 16 + l15];
        float cg = cgw[wave * 16 + l15];
#pragma unroll
        for (int m = 0; m < 2; m++) {
#pragma unroll
            for (int reg = 0; reg < 4; reg++) {
                float zv = zb[m * 16 + quad * 4 + reg];
                float s = fmaf(cs, zv, acc1[m][0][reg]);
                float t = fmaf(cg, zv, acc1[m][1][reg]);
                float gv = s / (1.f + __expf(-t));
                g[m][reg] = gv;
                int tl = m * 16 + quad * 4 + reg;
                int c = wave * 16 + l15;
                unsigned short hi = f2b(gv);
                sGhi[tl * GP + c] = hi;
                sGlo[tl * GP + c] = f2b(gv - b2f(hi));
            }
        }
    }
    __syncthreads();

    // ---- GEMM2: [skip;res]^T[t][o2], K=128; n=0 -> skip, n=1 -> res
    f32x4 acc2[2][2];
#pragma unroll
    for (int m = 0; m < 2; m++)
#pragma unroll
        for (int n = 0; n < 2; n++) acc2[m][n] = (f32x4){0.f, 0.f, 0.f, 0.f};

#pragma unroll
    for (int kk = 0; kk < 4; kk++) {
        s16x8 Ah[2], Al[2];
#pragma unroll
        for (int m = 0; m < 2; m++) {
            int off = (m * 16 + l15) * GP + kk * 32 + quad * 8;
            Ah[m] = *(const s16x8*)(sGhi + off);
            Al[m] = *(const s16x8*)(sGlo + off);
        }
#pragma unroll
        for (int n = 0; n < 2; n++) {
            int o2 = (wave + 8 * n) * 16 + l15;
            s16x8 Bh = *(const s16x8*)(WkrH + o2 * 128 + kk * 32 + quad * 8);
            s16x8 Bl = *(const s16x8*)(WkrL + o2 * 128 + kk * 32 + quad * 8);
#pragma unroll
            for (int m = 0; m < 2; m++) {
                acc2[m][n] = __builtin_amdgcn_mfma_f32_16x16x32_bf16(Ah[m], Bh, acc2[m][n], 0, 0, 0);
                acc2[m][n] = __builtin_amdgcn_mfma_f32_16x16x32_bf16(Al[m], Bh, acc2[m][n], 0, 0, 0);
                acc2[m][n] = __builtin_amdgcn_mfma_f32_16x16x32_bf16(Ah[m], Bl, acc2[m][n], 0, 0, 0);
            }
        }
    }

    // ---- epilogue: h_next = res + (first ? orig : g); skip accumulate.
    // Thread's (c,t) here matches its g[m][reg] exactly: c = wave*16+l15,
    // t = t0 + m*16 + quad*4 + reg.
#pragma unroll
    for (int m = 0; m < 2; m++) {
        int c = wave * 16 + l15;
#pragma unroll
        for (int reg = 0; reg < 4; reg++) {
            int t = t0 + m * 16 + quad * 4 + reg;
            size_t hidx = ((size_t)b * LP + PADT + t) * CC + c;
            size_t sidx = ((size_t)b * LL + t) * CC + c;
            float skp = acc2[m][0][reg];
            float res = acc2[m][1][reg];
            float hv, sv;
            if (first) {
                hv = res + unpacksum(hcur[hidx]);
                sv = skp;
            } else {
                hv = res + g[m][reg];
                sv = skp + skipbuf[sidx];
            }
            if (last) {
                size_t oidx = ((size_t)b * CC + c) * LL + t;
                out[oidx] = hv;
                out[(size_t)BB * CC * LL + oidx] = sv;
            } else {
                hnext[hidx] = packsplit(hv);
                skipbuf[sidx] = sv;
            }
        }
    }
}

extern "C" void kernel_launch(void* const* d_in, const int* in_sizes, int n_in,
                              void* d_out, int out_size, void* d_ws, size_t ws_size,
                              hipStream_t stream) {
    const float* x = (const float*)d_in[0];
    const float* z = (const float*)d_in[1];
    const float* w0 = (const float*)d_in[2];
    const float* b0 = (const float*)d_in[3];
    const float* sw = (const float*)d_in[4];
    const float* gw = (const float*)d_in[5];
    const float* csw = (const float*)d_in[6];
    const float* cgw = (const float*)d_in[7];
    const float* rew = (const float*)d_in[8];
    const float* skw = (const float*)d_in[9];

    const size_t HSZ = (size_t)BB * LP * CC;           // padded packed h, uint32
    const size_t NCL = (size_t)BB * CC * LL;           // 16,777,216
    unsigned int* hA = (unsigned int*)d_ws;
    unsigned int* hB = hA + HSZ;
    float* skipb = (float*)(hB + HSZ);
    unsigned short* WsgH = (unsigned short*)(skipb + NCL);
    unsigned short* WsgL = WsgH + (size_t)RR * 256 * 256;
    unsigned short* WkrH = WsgL + (size_t)RR * 256 * 256;
    unsigned short* WkrL = WkrH + (size_t)RR * 256 * 128;

    prep_kernel<<<RR * 256 * 256 / 256, 256, 0, stream>>>(sw, gw, skw, rew, WsgH, WsgL, WkrH, WkrL);
    zero_pad_kernel<<<BB * PADT * CC / 256, 256, 0, stream>>>(hA, hB);
    proj_kernel<<<NCL / 256, 256, 0, stream>>>(x, w0, b0, hA);

    unsigned int* hc = hA;
    unsigned int* hn = hB;
    for (int ii = 0; ii < RR; ii++) {
        int d = 1 << ii;
        int off0 = d + 1;   // taps: t-(d+1) (tap0) and t-1 (tap1); holds for ii==0 (pad=K=2)
        layer_kernel<<<BB * (LL / TT), 512, 0, stream>>>(
            hc, hn, skipb,
            WsgH + (size_t)ii * 256 * 256, WsgL + (size_t)ii * 256 * 256,
            WkrH + (size_t)ii * 256 * 128, WkrL + (size_t)ii * 256 * 128,
            csw + ii * CC, cgw + ii * CC, z,
            (float*)d_out, off0, ii == 0 ? 1 : 0, ii == RR - 1 ? 1 : 0);
        unsigned int* tmp = hc; hc = hn; hn = tmp;
    }
}

// Round 6
// 1500.679 us; speedup vs baseline: 1.7992x; 1.7992x over previous
//
#include <hip/hip_runtime.h>
#include <hip/hip_bf16.h>

#define RR 8
#define BB 32
#define CIN 21
#define CC 128
#define LL 4096
#define TT 64     // time-tile (M=64)
#define SROW 132  // sH row stride in dwords: 128 + 4 pad (528B, 16B-aligned)
#define GP 136    // sG row stride (shorts): 128 + 8 pad
#define PADT 132  // zeroed halo rows per batch (>= max shift 129)
#define LP (LL + PADT)

typedef short s16x8 __attribute__((ext_vector_type(8)));
typedef float f32x4 __attribute__((ext_vector_type(4)));

__device__ __forceinline__ unsigned short f2b(float f) {
    __hip_bfloat16 h = __float2bfloat16(f);
    return *reinterpret_cast<unsigned short*>(&h);
}
__device__ __forceinline__ float b2f(unsigned short u) {
    __hip_bfloat16 h;
    *reinterpret_cast<unsigned short*>(&h) = u;
    return __bfloat162float(h);
}
__device__ __forceinline__ unsigned int packsplit(float v) {
    unsigned short hi = f2b(v);
    unsigned short lo = f2b(v - b2f(hi));
    return ((unsigned int)hi << 16) | (unsigned int)lo;
}
__device__ __forceinline__ float unpacksum(unsigned int u) {
    return b2f((unsigned short)(u >> 16)) + b2f((unsigned short)(u & 0xffffu));
}

// 8 packed (hi|lo) uint32 -> s16x8 hi-plane + s16x8 lo-plane via v_perm
__device__ __forceinline__ void unpack8(const unsigned int* p, s16x8& hi, s16x8& lo) {
    uint4 u0 = *reinterpret_cast<const uint4*>(p);
    uint4 u1 = *reinterpret_cast<const uint4*>(p + 4);
    union { int i[4]; s16x8 v; } H, L;
    H.i[0] = __builtin_amdgcn_perm(u0.y, u0.x, 0x07060302u);
    L.i[0] = __builtin_amdgcn_perm(u0.y, u0.x, 0x05040100u);
    H.i[1] = __builtin_amdgcn_perm(u0.w, u0.z, 0x07060302u);
    L.i[1] = __builtin_amdgcn_perm(u0.w, u0.z, 0x05040100u);
    H.i[2] = __builtin_amdgcn_perm(u1.y, u1.x, 0x07060302u);
    L.i[2] = __builtin_amdgcn_perm(u1.y, u1.x, 0x05040100u);
    H.i[3] = __builtin_amdgcn_perm(u1.w, u1.z, 0x07060302u);
    L.i[3] = __builtin_amdgcn_perm(u1.w, u1.z, 0x05040100u);
    hi = H.v; lo = L.v;
}

// ---- pack weights to split-bf16 (hi/lo) MFMA rows.
__global__ void prep_kernel(const float* __restrict__ sw, const float* __restrict__ gw,
                            const float* __restrict__ skw, const float* __restrict__ rew,
                            unsigned short* __restrict__ WsgH, unsigned short* __restrict__ WsgL,
                            unsigned short* __restrict__ WkrH, unsigned short* __restrict__ WkrL) {
    int idx = blockIdx.x * 256 + threadIdx.x;        // over R*256*256 = 524288
    int r = idx >> 16;
    int rem = idx & 65535;
    int o = rem >> 8;
    int k = rem & 255;
    int c = k & 127;
    int tap = k >> 7;
    float v = (o < 128) ? sw[(((r * 128 + o) * 128 + c) << 1) + tap]
                        : gw[(((r * 128 + (o - 128)) * 128 + c) << 1) + tap];
    unsigned short hi = f2b(v);
    WsgH[idx] = hi;
    WsgL[idx] = f2b(v - b2f(hi));
    if (idx < RR * 256 * 128) {
        int r2 = idx >> 15;
        int rem2 = idx & 32767;
        int o2 = rem2 >> 7;
        int c2 = rem2 & 127;
        float v2 = (o2 < 128) ? skw[(r2 * 128 + o2) * 128 + c2]
                              : rew[(r2 * 128 + (o2 - 128)) * 128 + c2];
        unsigned short hi2 = f2b(v2);
        WkrH[idx] = hi2;
        WkrL[idx] = f2b(v2 - b2f(hi2));
    }
}

// ---- zero the halo rows of both h buffers
__global__ void zero_pad_kernel(unsigned int* __restrict__ hA, unsigned int* __restrict__ hB) {
    int idx = blockIdx.x * 256 + threadIdx.x;        // over BB*PADT*CC
    int c = idx & 127;
    int r = (idx >> 7) % PADT;
    int b = idx / (PADT * 128);
    size_t off = ((size_t)b * LP + r) * CC + c;
    hA[off] = 0u;
    hB[off] = 0u;
}

// ---- input projection: h0 packed split-bf16 [b][PADT+t][c]
__global__ void proj_kernel(const float* __restrict__ x, const float* __restrict__ w0,
                            const float* __restrict__ b0, unsigned int* __restrict__ h0) {
    int idx = blockIdx.x * 256 + threadIdx.x;
    int c = idx & 127;
    int t = (idx >> 7) & (LL - 1);
    int b = idx >> 19;
    const float* xb = x + (size_t)b * CIN * LL + t;
    const float* w = w0 + c * CIN;
    float acc = b0[c];
#pragma unroll
    for (int i = 0; i < CIN; i++) acc = fmaf(w[i], xb[i * LL], acc);
    h0[((size_t)b * LP + PADT + t) * CC + c] = packsplit(acc);
}

// ---- fused split-bf16 MFMA layer; M=64 tile, 8 waves. One 64-row LDS window,
// taps processed sequentially; window-1 prefetched to regs during GEMM1-win0
// (T14 split). sG aliases the window buffer. g kept in registers.
__global__ void __launch_bounds__(512, 4) layer_kernel(
    const unsigned int* __restrict__ hcur,     // packed [B][LP][C], data at row PADT
    unsigned int* __restrict__ hnext,
    float* __restrict__ skipbuf,               // f32 [B][L][C]
    const unsigned short* __restrict__ WsgH, const unsigned short* __restrict__ WsgL,
    const unsigned short* __restrict__ WkrH, const unsigned short* __restrict__ WkrL,
    const float* __restrict__ csw, const float* __restrict__ cgw,
    const float* __restrict__ z,
    float* __restrict__ out,                   // f32 [2][B][C][L] on last layer
    int off0, int first, int last) {
    __shared__ unsigned int sBuf[2 * TT * GP / 2];        // 34,816 B (8704 dw); sH uses [TT][SROW]
    unsigned short* sGhi = (unsigned short*)sBuf;         // [TT][GP]
    unsigned short* sGlo = sGhi + TT * GP;

    int tid = threadIdx.x;
    int b = blockIdx.x >> 6;                   // 32 batches
    int t0 = (blockIdx.x & 63) * TT;           // 64 t-tiles

    int wave = tid >> 6;                       // 0..7
    int lane = tid & 63;
    int l15 = lane & 15;
    int quad = lane >> 4;

    const unsigned int* hb = hcur + (size_t)b * LP * CC;

    // ---- stage win0 (tap0: shift=off0) into LDS; issue win1 (t-1) loads to regs
    uint4 stg[4];
    {
        const unsigned int* src0 = hb + (size_t)(PADT + t0 - off0) * CC;
#pragma unroll
        for (int j = 0; j < 4; j++) {
            int flat = tid + 512 * j;          // 0..2047
            int row = flat >> 5;               // 0..63
            int c16 = flat & 31;
            uint4 v = *(const uint4*)(src0 + (size_t)row * CC + c16 * 4);
            *(uint4*)(sBuf + row * SROW + c16 * 4) = v;
        }
        const unsigned int* src1 = hb + (size_t)(PADT + t0 - 1) * CC;
#pragma unroll
        for (int j = 0; j < 4; j++) {
            int flat = tid + 512 * j;
            int row = flat >> 5;
            int c16 = flat & 31;
            stg[j] = *(const uint4*)(src1 + (size_t)row * CC + c16 * 4);
        }
    }
    __syncthreads();

    // ---- GEMM1: [sig;gate]^T[t][o], M=64, N=256, K=256 (2 taps x 128), 3-pass.
    f32x4 acc1[4][2];
#pragma unroll
    for (int m = 0; m < 4; m++)
#pragma unroll
        for (int n = 0; n < 2; n++) acc1[m][n] = (f32x4){0.f, 0.f, 0.f, 0.f};

    // --- tap0 segment (B cols kk=0..3)
#pragma unroll
    for (int kk = 0; kk < 4; kk++) {
        const int cb = kk * 32 + quad * 8;
        s16x8 Ah[4], Al[4];
#pragma unroll
        for (int m = 0; m < 4; m++)
            unpack8(sBuf + (m * 16 + l15) * SROW + cb, Ah[m], Al[m]);
#pragma unroll
        for (int n = 0; n < 2; n++) {
            int o = (wave + 8 * n) * 16 + l15;
            s16x8 Bh = *(const s16x8*)(WsgH + o * 256 + kk * 32 + quad * 8);
            s16x8 Bl = *(const s16x8*)(WsgL + o * 256 + kk * 32 + quad * 8);
#pragma unroll
            for (int m = 0; m < 4; m++) {
                acc1[m][n] = __builtin_amdgcn_mfma_f32_16x16x32_bf16(Ah[m], Bh, acc1[m][n], 0, 0, 0);
                acc1[m][n] = __builtin_amdgcn_mfma_f32_16x16x32_bf16(Al[m], Bh, acc1[m][n], 0, 0, 0);
                acc1[m][n] = __builtin_amdgcn_mfma_f32_16x16x32_bf16(Ah[m], Bl, acc1[m][n], 0, 0, 0);
            }
        }
    }
    __syncthreads();   // tap0 LDS reads done

    // --- write win1 (t-1) regs -> LDS
#pragma unroll
    for (int j = 0; j < 4; j++) {
        int flat = tid + 512 * j;
        int row = flat >> 5;
        int c16 = flat & 31;
        *(uint4*)(sBuf + row * SROW + c16 * 4) = stg[j];
    }
    __syncthreads();

    // --- tap1 segment (B cols kk=4..7)
#pragma unroll
    for (int kk = 0; kk < 4; kk++) {
        const int cb = kk * 32 + quad * 8;
        s16x8 Ah[4], Al[4];
#pragma unroll
        for (int m = 0; m < 4; m++)
            unpack8(sBuf + (m * 16 + l15) * SROW + cb, Ah[m], Al[m]);
#pragma unroll
        for (int n = 0; n < 2; n++) {
            int o = (wave + 8 * n) * 16 + l15;
            s16x8 Bh = *(const s16x8*)(WsgH + o * 256 + (kk + 4) * 32 + quad * 8);
            s16x8 Bl = *(const s16x8*)(WsgL + o * 256 + (kk + 4) * 32 + quad * 8);
#pragma unroll
            for (int m = 0; m < 4; m++) {
                acc1[m][n] = __builtin_amdgcn_mfma_f32_16x16x32_bf16(Ah[m], Bh, acc1[m][n], 0, 0, 0);
                acc1[m][n] = __builtin_amdgcn_mfma_f32_16x16x32_bf16(Al[m], Bh, acc1[m][n], 0, 0, 0);
                acc1[m][n] = __builtin_amdgcn_mfma_f32_16x16x32_bf16(Ah[m], Bl, acc1[m][n], 0, 0, 0);
            }
        }
    }

    // ---- conditioning + gated activation; g kept in registers (c = wave*16+l15)
    float g[4][4];
    {
        const float* zb = z + (size_t)b * LL + t0;
        float cs = csw[wave * 16 + l15];
        float cg = cgw[wave * 16 + l15];
#pragma unroll
        for (int m = 0; m < 4; m++)
#pragma unroll
            for (int reg = 0; reg < 4; reg++) {
                float zv = zb[m * 16 + quad * 4 + reg];
                float s = fmaf(cs, zv, acc1[m][0][reg]);
                float t = fmaf(cg, zv, acc1[m][1][reg]);
                g[m][reg] = s / (1.f + __expf(-t));
            }
    }
    __syncthreads();   // tap1 LDS reads done before sG overwrites the window

    {
        int c = wave * 16 + l15;
#pragma unroll
        for (int m = 0; m < 4; m++)
#pragma unroll
            for (int reg = 0; reg < 4; reg++) {
                int tl = m * 16 + quad * 4 + reg;
                float gv = g[m][reg];
                unsigned short hi = f2b(gv);
                sGhi[tl * GP + c] = hi;
                sGlo[tl * GP + c] = f2b(gv - b2f(hi));
            }
    }
    __syncthreads();

    // ---- GEMM2: [skip;res]^T[t][o2], K=128; n=0 -> skip, n=1 -> res
    f32x4 acc2[4][2];
#pragma unroll
    for (int m = 0; m < 4; m++)
#pragma unroll
        for (int n = 0; n < 2; n++) acc2[m][n] = (f32x4){0.f, 0.f, 0.f, 0.f};

#pragma unroll
    for (int kk = 0; kk < 4; kk++) {
        s16x8 Ah[4], Al[4];
#pragma unroll
        for (int m = 0; m < 4; m++) {
            int off = (m * 16 + l15) * GP + kk * 32 + quad * 8;
            Ah[m] = *(const s16x8*)(sGhi + off);
            Al[m] = *(const s16x8*)(sGlo + off);
        }
#pragma unroll
        for (int n = 0; n < 2; n++) {
            int o2 = (wave + 8 * n) * 16 + l15;
            s16x8 Bh = *(const s16x8*)(WkrH + o2 * 128 + kk * 32 + quad * 8);
            s16x8 Bl = *(const s16x8*)(WkrL + o2 * 128 + kk * 32 + quad * 8);
#pragma unroll
            for (int m = 0; m < 4; m++) {
                acc2[m][n] = __builtin_amdgcn_mfma_f32_16x16x32_bf16(Ah[m], Bh, acc2[m][n], 0, 0, 0);
                acc2[m][n] = __builtin_amdgcn_mfma_f32_16x16x32_bf16(Al[m], Bh, acc2[m][n], 0, 0, 0);
                acc2[m][n] = __builtin_amdgcn_mfma_f32_16x16x32_bf16(Ah[m], Bl, acc2[m][n], 0, 0, 0);
            }
        }
    }

    // ---- epilogue: h_next = res + (first ? orig : g); skip accumulate.
    // Thread's (c,t) matches its g[m][reg]: c = wave*16+l15, t = t0+m*16+quad*4+reg.
#pragma unroll
    for (int m = 0; m < 4; m++) {
        int c = wave * 16 + l15;
#pragma unroll
        for (int reg = 0; reg < 4; reg++) {
            int t = t0 + m * 16 + quad * 4 + reg;
            size_t hidx = ((size_t)b * LP + PADT + t) * CC + c;
            size_t sidx = ((size_t)b * LL + t) * CC + c;
            float skp = acc2[m][0][reg];
            float res = acc2[m][1][reg];
            float hv, sv;
            if (first) {
                hv = res + unpacksum(hcur[hidx]);
                sv = skp;
            } else {
                hv = res + g[m][reg];
                sv = skp + skipbuf[sidx];
            }
            if (last) {
                size_t oidx = ((size_t)b * CC + c) * LL + t;
                out[oidx] = hv;
                out[(size_t)BB * CC * LL + oidx] = sv;
            } else {
                hnext[hidx] = packsplit(hv);
                skipbuf[sidx] = sv;
            }
        }
    }
}

extern "C" void kernel_launch(void* const* d_in, const int* in_sizes, int n_in,
                              void* d_out, int out_size, void* d_ws, size_t ws_size,
                              hipStream_t stream) {
    const float* x = (const float*)d_in[0];
    const float* z = (const float*)d_in[1];
    const float* w0 = (const float*)d_in[2];
    const float* b0 = (const float*)d_in[3];
    const float* sw = (const float*)d_in[4];
    const float* gw = (const float*)d_in[5];
    const float* csw = (const float*)d_in[6];
    const float* cgw = (const float*)d_in[7];
    const float* rew = (const float*)d_in[8];
    const float* skw = (const float*)d_in[9];

    const size_t HSZ = (size_t)BB * LP * CC;           // padded packed h, uint32
    const size_t NCL = (size_t)BB * CC * LL;           // 16,777,216
    unsigned int* hA = (unsigned int*)d_ws;
    unsigned int* hB = hA + HSZ;
    float* skipb = (float*)(hB + HSZ);
    unsigned short* WsgH = (unsigned short*)(skipb + NCL);
    unsigned short* WsgL = WsgH + (size_t)RR * 256 * 256;
    unsigned short* WkrH = WsgL + (size_t)RR * 256 * 256;
    unsigned short* WkrL = WkrH + (size_t)RR * 256 * 128;

    prep_kernel<<<RR * 256 * 256 / 256, 256, 0, stream>>>(sw, gw, skw, rew, WsgH, WsgL, WkrH, WkrL);
    zero_pad_kernel<<<BB * PADT * 128 / 256, 256, 0, stream>>>(hA, hB);
    proj_kernel<<<NCL / 256, 256, 0, stream>>>(x, w0, b0, hA);

    unsigned int* hc = hA;
    unsigned int* hn = hB;
    for (int ii = 0; ii < RR; ii++) {
        int d = 1 << ii;
        int off0 = d + 1;   // taps: t-(d+1) (tap0) and t-1 (tap1); holds for ii==0 (pad=K=2)
        layer_kernel<<<BB * (LL / TT), 512, 0, stream>>>(
            hc, hn, skipb,
            WsgH + (size_t)ii * 256 * 256, WsgL + (size_t)ii * 256 * 256,
            WkrH + (size_t)ii * 256 * 128, WkrL + (size_t)ii * 256 * 128,
            csw + ii * CC, cgw + ii * CC, z,
            (float*)d_out, off0, ii == 0 ? 1 : 0, ii == RR - 1 ? 1 : 0);
        unsigned int* tmp = hc; hc = hn; hn = tmp;
    }
}

// Round 7
// 1322.485 us; speedup vs baseline: 2.0416x; 1.1347x over previous
//
#include <hip/hip_runtime.h>
#include <hip/hip_bf16.h>

#define RR 8
#define BB 32
#define CIN 21
#define CC 128
#define LL 4096
#define TT 64     // time-tile (M=64)
#define GP 136    // sG row stride (shorts): 128 + 8 pad
#define PADT 132  // zeroed halo rows per batch (>= max shift 129)
#define LP (LL + PADT)

typedef short s16x8 __attribute__((ext_vector_type(8)));
typedef float f32x4 __attribute__((ext_vector_type(4)));
typedef unsigned int __attribute__((address_space(1))) gu32;
typedef unsigned int __attribute__((address_space(3))) lu32;

__device__ __forceinline__ unsigned short f2b(float f) {
    __hip_bfloat16 h = __float2bfloat16(f);
    return *reinterpret_cast<unsigned short*>(&h);
}
__device__ __forceinline__ float b2f(unsigned short u) {
    __hip_bfloat16 h;
    *reinterpret_cast<unsigned short*>(&h) = u;
    return __bfloat162float(h);
}
__device__ __forceinline__ unsigned int packsplit(float v) {
    unsigned short hi = f2b(v);
    unsigned short lo = f2b(v - b2f(hi));
    return ((unsigned int)hi << 16) | (unsigned int)lo;
}
__device__ __forceinline__ float unpacksum(unsigned int u) {
    return b2f((unsigned short)(u >> 16)) + b2f((unsigned short)(u & 0xffffu));
}

// two uint4 of packed (hi|lo) -> s16x8 hi-plane + lo-plane via v_perm
__device__ __forceinline__ void unpack2(uint4 u0, uint4 u1, s16x8& hi, s16x8& lo) {
    union { int i[4]; s16x8 v; } H, L;
    H.i[0] = __builtin_amdgcn_perm(u0.y, u0.x, 0x07060302u);
    L.i[0] = __builtin_amdgcn_perm(u0.y, u0.x, 0x05040100u);
    H.i[1] = __builtin_amdgcn_perm(u0.w, u0.z, 0x07060302u);
    L.i[1] = __builtin_amdgcn_perm(u0.w, u0.z, 0x05040100u);
    H.i[2] = __builtin_amdgcn_perm(u1.y, u1.x, 0x07060302u);
    L.i[2] = __builtin_amdgcn_perm(u1.y, u1.x, 0x05040100u);
    H.i[3] = __builtin_amdgcn_perm(u1.w, u1.z, 0x07060302u);
    L.i[3] = __builtin_amdgcn_perm(u1.w, u1.z, 0x05040100u);
    hi = H.v; lo = L.v;
}

// ---- pack weights to split-bf16 (hi/lo) MFMA rows.
__global__ void prep_kernel(const float* __restrict__ sw, const float* __restrict__ gw,
                            const float* __restrict__ skw, const float* __restrict__ rew,
                            unsigned short* __restrict__ WsgH, unsigned short* __restrict__ WsgL,
                            unsigned short* __restrict__ WkrH, unsigned short* __restrict__ WkrL) {
    int idx = blockIdx.x * 256 + threadIdx.x;        // over R*256*256 = 524288
    int r = idx >> 16;
    int rem = idx & 65535;
    int o = rem >> 8;
    int k = rem & 255;
    int c = k & 127;
    int tap = k >> 7;
    float v = (o < 128) ? sw[(((r * 128 + o) * 128 + c) << 1) + tap]
                        : gw[(((r * 128 + (o - 128)) * 128 + c) << 1) + tap];
    unsigned short hi = f2b(v);
    WsgH[idx] = hi;
    WsgL[idx] = f2b(v - b2f(hi));
    if (idx < RR * 256 * 128) {
        int r2 = idx >> 15;
        int rem2 = idx & 32767;
        int o2 = rem2 >> 7;
        int c2 = rem2 & 127;
        float v2 = (o2 < 128) ? skw[(r2 * 128 + o2) * 128 + c2]
                              : rew[(r2 * 128 + (o2 - 128)) * 128 + c2];
        unsigned short hi2 = f2b(v2);
        WkrH[idx] = hi2;
        WkrL[idx] = f2b(v2 - b2f(hi2));
    }
}

// ---- zero the halo rows of both h buffers
__global__ void zero_pad_kernel(unsigned int* __restrict__ hA, unsigned int* __restrict__ hB) {
    int idx = blockIdx.x * 256 + threadIdx.x;        // over BB*PADT*CC
    int c = idx & 127;
    int r = (idx >> 7) % PADT;
    int b = idx / (PADT * 128);
    size_t off = ((size_t)b * LP + r) * CC + c;
    hA[off] = 0u;
    hB[off] = 0u;
}

// ---- input projection: h0 packed split-bf16 [b][PADT+t][c]
__global__ void proj_kernel(const float* __restrict__ x, const float* __restrict__ w0,
                            const float* __restrict__ b0, unsigned int* __restrict__ h0) {
    int idx = blockIdx.x * 256 + threadIdx.x;
    int c = idx & 127;
    int t = (idx >> 7) & (LL - 1);
    int b = idx >> 19;
    const float* xb = x + (size_t)b * CIN * LL + t;
    const float* w = w0 + c * CIN;
    float acc = b0[c];
#pragma unroll
    for (int i = 0; i < CIN; i++) acc = fmaf(w[i], xb[i * LL], acc);
    h0[((size_t)b * LP + PADT + t) * CC + c] = packsplit(acc);
}

// ---- fused split-bf16 MFMA layer; M=64 tile, 8 waves. Both tap-windows
// async-staged via global_load_lds into linear LDS with XOR-swizzled source
// (read side applies the same involution). sG aliases the windows after
// GEMM1. g kept in registers. 3 barriers total.
__global__ void __launch_bounds__(512, 4) layer_kernel(
    const unsigned int* __restrict__ hcur,     // packed [B][LP][C], data at row PADT
    unsigned int* __restrict__ hnext,
    float* __restrict__ skipbuf,               // f32 [B][L][C]
    const unsigned short* __restrict__ WsgH, const unsigned short* __restrict__ WsgL,
    const unsigned short* __restrict__ WkrH, const unsigned short* __restrict__ WkrL,
    const float* __restrict__ csw, const float* __restrict__ cgw,
    const float* __restrict__ z,
    float* __restrict__ out,                   // f32 [2][B][C][L] on last layer
    int off0, int first, int last) {
    __shared__ unsigned int sBuf[16384];       // 64 KiB: win0 [0,8192), win1 [8192,16384)
    unsigned short* sGhi = (unsigned short*)sBuf;   // [TT][GP] aliases win region
    unsigned short* sGlo = sGhi + TT * GP;

    int tid = threadIdx.x;
    int b = blockIdx.x >> 6;                   // 32 batches
    int t0 = (blockIdx.x & 63) * TT;           // 64 t-tiles

    int wave = tid >> 6;                       // 0..7
    int lane = tid & 63;
    int l15 = lane & 15;
    int quad = lane >> 4;

    const unsigned int* hb = hcur + (size_t)b * LP * CC;

    // ---- stage both windows (win0: t-off0, win1: t-1) via global_load_lds.
    // LDS dest linear (flat*16B); source unit pre-swizzled: u_l = u_d ^ (row&7).
    {
        const unsigned int* src0 = hb + (size_t)(PADT + t0 - off0) * CC;
        const unsigned int* src1 = hb + (size_t)(PADT + t0 - 1) * CC;
#pragma unroll
        for (int jj = 0; jj < 8; jj++) {
            int flat = tid + 512 * jj;         // 0..4095 (16B units over 64KB)
            int row = (flat >> 5) & 63;
            int ud = flat & 31;
            const unsigned int* srcw = (jj < 4) ? src0 : src1;
            const unsigned int* gp = srcw + (size_t)row * CC + ((ud ^ (row & 7)) << 2);
            unsigned int* lp = sBuf + flat * 4;
            __builtin_amdgcn_global_load_lds((const gu32*)gp, (lu32*)lp, 16, 0, 0);
        }
    }
    __syncthreads();

    // ---- GEMM1: [sig;gate]^T[t][o], M=64, N=256, K=256 (2 taps x 128), 3-pass.
    f32x4 acc1[4][2];
#pragma unroll
    for (int m = 0; m < 4; m++)
#pragma unroll
        for (int n = 0; n < 2; n++) acc1[m][n] = (f32x4){0.f, 0.f, 0.f, 0.f};

#pragma unroll
    for (int kk = 0; kk < 8; kk++) {
        const int win = kk >> 2;
        const int U = (kk & 3) * 8 + quad * 2;       // logical 16B-unit (even)
        s16x8 Ah[4], Al[4];
#pragma unroll
        for (int m = 0; m < 4; m++) {
            int r = m * 16 + l15;
            const unsigned int* base = sBuf + win * 8192 + r * 128;
            int s = r & 7;
            uint4 x0 = *(const uint4*)(base + ((U ^ s) << 2));
            uint4 x1 = *(const uint4*)(base + (((U + 1) ^ s) << 2));
            unpack2(x0, x1, Ah[m], Al[m]);
        }
#pragma unroll
        for (int n = 0; n < 2; n++) {
            int o = (wave + 8 * n) * 16 + l15;
            s16x8 Bh = *(const s16x8*)(WsgH + o * 256 + kk * 32 + quad * 8);
            s16x8 Bl = *(const s16x8*)(WsgL + o * 256 + kk * 32 + quad * 8);
#pragma unroll
            for (int m = 0; m < 4; m++) {
                acc1[m][n] = __builtin_amdgcn_mfma_f32_16x16x32_bf16(Ah[m], Bh, acc1[m][n], 0, 0, 0);
                acc1[m][n] = __builtin_amdgcn_mfma_f32_16x16x32_bf16(Al[m], Bh, acc1[m][n], 0, 0, 0);
                acc1[m][n] = __builtin_amdgcn_mfma_f32_16x16x32_bf16(Ah[m], Bl, acc1[m][n], 0, 0, 0);
            }
        }
    }

    // ---- conditioning + gated activation; g kept in registers (c = wave*16+l15)
    float g[4][4];
    {
        const float* zb = z + (size_t)b * LL + t0;
        float cs = csw[wave * 16 + l15];
        float cg = cgw[wave * 16 + l15];
#pragma unroll
        for (int m = 0; m < 4; m++)
#pragma unroll
            for (int reg = 0; reg < 4; reg++) {
                float zv = zb[m * 16 + quad * 4 + reg];
                float s = fmaf(cs, zv, acc1[m][0][reg]);
                float t = fmaf(cg, zv, acc1[m][1][reg]);
                g[m][reg] = s / (1.f + __expf(-t));
            }
    }
    __syncthreads();   // GEMM1 window reads done before sG overwrites

    {
        int c = wave * 16 + l15;
#pragma unroll
        for (int m = 0; m < 4; m++)
#pragma unroll
            for (int reg = 0; reg < 4; reg++) {
                int tl = m * 16 + quad * 4 + reg;
                float gv = g[m][reg];
                unsigned short hi = f2b(gv);
                sGhi[tl * GP + c] = hi;
                sGlo[tl * GP + c] = f2b(gv - b2f(hi));
            }
    }
    __syncthreads();

    // ---- GEMM2: [skip;res]^T[t][o2], K=128; n=0 -> skip, n=1 -> res
    f32x4 acc2[4][2];
#pragma unroll
    for (int m = 0; m < 4; m++)
#pragma unroll
        for (int n = 0; n < 2; n++) acc2[m][n] = (f32x4){0.f, 0.f, 0.f, 0.f};

#pragma unroll
    for (int kk = 0; kk < 4; kk++) {
        s16x8 Ah[4], Al[4];
#pragma unroll
        for (int m = 0; m < 4; m++) {
            int off = (m * 16 + l15) * GP + kk * 32 + quad * 8;
            Ah[m] = *(const s16x8*)(sGhi + off);
            Al[m] = *(const s16x8*)(sGlo + off);
        }
#pragma unroll
        for (int n = 0; n < 2; n++) {
            int o2 = (wave + 8 * n) * 16 + l15;
            s16x8 Bh = *(const s16x8*)(WkrH + o2 * 128 + kk * 32 + quad * 8);
            s16x8 Bl = *(const s16x8*)(WkrL + o2 * 128 + kk * 32 + quad * 8);
#pragma unroll
            for (int m = 0; m < 4; m++) {
                acc2[m][n] = __builtin_amdgcn_mfma_f32_16x16x32_bf16(Ah[m], Bh, acc2[m][n], 0, 0, 0);
                acc2[m][n] = __builtin_amdgcn_mfma_f32_16x16x32_bf16(Al[m], Bh, acc2[m][n], 0, 0, 0);
                acc2[m][n] = __builtin_amdgcn_mfma_f32_16x16x32_bf16(Ah[m], Bl, acc2[m][n], 0, 0, 0);
            }
        }
    }

    // ---- epilogue: h_next = res + (first ? orig : g); skip accumulate.
#pragma unroll
    for (int m = 0; m < 4; m++) {
        int c = wave * 16 + l15;
#pragma unroll
        for (int reg = 0; reg < 4; reg++) {
            int t = t0 + m * 16 + quad * 4 + reg;
            size_t hidx = ((size_t)b * LP + PADT + t) * CC + c;
            size_t sidx = ((size_t)b * LL + t) * CC + c;
            float skp = acc2[m][0][reg];
            float res = acc2[m][1][reg];
            float hv, sv;
            if (first) {
                hv = res + unpacksum(hcur[hidx]);
                sv = skp;
            } else {
                hv = res + g[m][reg];
                sv = skp + skipbuf[sidx];
            }
            if (last) {
                size_t oidx = ((size_t)b * CC + c) * LL + t;
                out[oidx] = hv;
                out[(size_t)BB * CC * LL + oidx] = sv;
            } else {
                hnext[hidx] = packsplit(hv);
                skipbuf[sidx] = sv;
            }
        }
    }
}

extern "C" void kernel_launch(void* const* d_in, const int* in_sizes, int n_in,
                              void* d_out, int out_size, void* d_ws, size_t ws_size,
                              hipStream_t stream) {
    const float* x = (const float*)d_in[0];
    const float* z = (const float*)d_in[1];
    const float* w0 = (const float*)d_in[2];
    const float* b0 = (const float*)d_in[3];
    const float* sw = (const float*)d_in[4];
    const float* gw = (const float*)d_in[5];
    const float* csw = (const float*)d_in[6];
    const float* cgw = (const float*)d_in[7];
    const float* rew = (const float*)d_in[8];
    const float* skw = (const float*)d_in[9];

    const size_t HSZ = (size_t)BB * LP * CC;           // padded packed h, uint32
    const size_t NCL = (size_t)BB * CC * LL;           // 16,777,216
    unsigned int* hA = (unsigned int*)d_ws;
    unsigned int* hB = hA + HSZ;
    float* skipb = (float*)(hB + HSZ);
    unsigned short* WsgH = (unsigned short*)(skipb + NCL);
    unsigned short* WsgL = WsgH + (size_t)RR * 256 * 256;
    unsigned short* WkrH = WsgL + (size_t)RR * 256 * 256;
    unsigned short* WkrL = WkrH + (size_t)RR * 256 * 128;

    prep_kernel<<<RR * 256 * 256 / 256, 256, 0, stream>>>(sw, gw, skw, rew, WsgH, WsgL, WkrH, WkrL);
    zero_pad_kernel<<<BB * PADT * 128 / 256, 256, 0, stream>>>(hA, hB);
    proj_kernel<<<NCL / 256, 256, 0, stream>>>(x, w0, b0, hA);

    unsigned int* hc = hA;
    unsigned int* hn = hB;
    for (int ii = 0; ii < RR; ii++) {
        int d = 1 << ii;
        int off0 = d + 1;   // taps: t-(d+1) (tap0) and t-1 (tap1); holds for ii==0 (pad=K=2)
        layer_kernel<<<BB * (LL / TT), 512, 0, stream>>>(
            hc, hn, skipb,
            WsgH + (size_t)ii * 256 * 256, WsgL + (size_t)ii * 256 * 256,
            WkrH + (size_t)ii * 256 * 128, WkrL + (size_t)ii * 256 * 128,
            csw + ii * CC, cgw + ii * CC, z,
            (float*)d_out, off0, ii == 0 ? 1 : 0, ii == RR - 1 ? 1 : 0);
        unsigned int* tmp = hc; hc = hn; hn = tmp;
    }
}